// Round 6
// baseline (181.728 us; speedup 1.0000x reference)
//
#include <hip/hip_runtime.h>
#include <hip/hip_bf16.h>

typedef unsigned short u16;
typedef unsigned long long u64;
typedef __attribute__((ext_vector_type(4))) float f32x4;
typedef __attribute__((ext_vector_type(8))) short bf16x8;

#define IN_F   4096
#define OUT_F  4096
#define BATCH  512

#define BM 64
#define BN 64
#define BK 64
#define NSTEPS (IN_F / BK)   // 64
#define DEPTH 4              // LDS ring, prefetch distance 3

#define NXCD    8
#define NB      256          // coarse buckets, 16 rows each
#define CHUNK   2048         // entries per bucket_scatter block
#define LCAP    24           // LDS bucket cap (mean 8, +5.6 sigma)
#define SEGCAP  2048         // per (xcd,bucket) seg cap (mean 781)
#define RCAP    512          // per-row list cap in build_w (mean 390, +6.1 sigma)
#define SCAP    128          // stash cap
#define GOVFCAP (2*1024*1024)

__device__ inline u16 f2bf(float f) {
    __hip_bfloat16 h = __float2bfloat16(f);   // RNE
    u16 u; __builtin_memcpy(&u, &h, 2); return u;
}

// Phase 1: LDS-aggregated coarse binning. Rounds 1-5 invariant: any per-element
// random global op (atomic OR 8B store) = one 32B sector at ~26G/s. So:
// aggregate 2048 entries in LDS, flush with 1 atomic per (block,bucket) and
// contiguous 64B runs per thread into per-XCD segments.
// bin entry: (i<<16)|(rlocal<<12)|col.  govf entry: (i<<24)|(row<<12)|col.
__global__ __launch_bounds__(256) void bucket_scatter(const int* __restrict__ row,
                                                      const int* __restrict__ col,
                                                      int* __restrict__ gcur,
                                                      u64* __restrict__ bins,
                                                      int* __restrict__ govf_cnt,
                                                      u64* __restrict__ govf, int nnz) {
    __shared__ u64 lbin[NB][LCAP];   // 48 KB
    __shared__ int lcur[NB];
    const int xcd = __builtin_amdgcn_s_getreg(20 | (3 << 11)) & (NXCD - 1);
    const int tid = threadIdx.x;
    lcur[tid] = 0;
    __syncthreads();

    int base = blockIdx.x * CHUNK + tid * 8;
    if (base + 8 <= nnz) {
        int4 r0 = ((const int4*)(row + base))[0];
        int4 r1 = ((const int4*)(row + base))[1];
        int4 c0 = ((const int4*)(col + base))[0];
        int4 c1 = ((const int4*)(col + base))[1];
        int rs[8] = {r0.x, r0.y, r0.z, r0.w, r1.x, r1.y, r1.z, r1.w};
        int cs[8] = {c0.x, c0.y, c0.z, c0.w, c1.x, c1.y, c1.z, c1.w};
#pragma unroll
        for (int j = 0; j < 8; j++) {
            int rr = rs[j], cc = cs[j], i = base + j;
            int bk = rr >> 4;
            int p = atomicAdd(&lcur[bk], 1);
            if (p < LCAP) {
                lbin[bk][p] = ((u64)i << 16) | (u64)((rr & 15) << 12) | (u64)cc;
            } else {
                int o = atomicAdd(govf_cnt, 1);
                if (o < GOVFCAP) govf[o] = ((u64)i << 24) | ((u64)rr << 12) | (u64)cc;
            }
        }
    } else {
        int e = nnz < base + 8 ? nnz : base + 8;
        for (int i = base; i < e; i++) {
            int rr = row[i], cc = col[i];
            int bk = rr >> 4;
            int p = atomicAdd(&lcur[bk], 1);
            if (p < LCAP) {
                lbin[bk][p] = ((u64)i << 16) | (u64)((rr & 15) << 12) | (u64)cc;
            } else {
                int o = atomicAdd(govf_cnt, 1);
                if (o < GOVFCAP) govf[o] = ((u64)i << 24) | ((u64)rr << 12) | (u64)cc;
            }
        }
    }
    __syncthreads();

    // flush: thread t owns bucket t (256 threads <-> 256 buckets)
    int cnt = lcur[tid];
    if (cnt > LCAP) cnt = LCAP;
    if (cnt > 0) {
        int gb = (xcd << 8) | tid;
        int b0 = atomicAdd(&gcur[gb], cnt);
        u64* seg = bins + (size_t)gb * SEGCAP;
        for (int k = 0; k < cnt; k++) {
            u64 e = lbin[tid][k];
            int p = b0 + k;
            if (p < SEGCAP) {
                seg[p] = e;
            } else {
                int rr = (tid << 4) | ((int)(e >> 12) & 15);
                int o = atomicAdd(govf_cnt, 1);
                if (o < GOVFCAP) govf[o] = ((e >> 16) << 24) | ((u64)rr << 12) | (e & 4095);
            }
        }
    }
}

// Phase 2: one block per bucket (16 rows). Load 8 per-XCD segs coalesced,
// LDS-scatter to per-row lists, resolve last-write-wins (max global index,
// order-independent) via aux[4096], gather w, stream out bf16 rows.
__global__ __launch_bounds__(256) void build_w(const int* __restrict__ gcur,
                                               const u64* __restrict__ bins,
                                               const int* __restrict__ govf_cnt,
                                               const u64* __restrict__ govf,
                                               const float* __restrict__ w,
                                               u16* __restrict__ Wbf) {
    __shared__ u64 lists[16][RCAP];   // 64 KB
    __shared__ u64 stash[SCAP];       // 1 KB
    __shared__ int aux[IN_F];         // 16 KB
    __shared__ int lcur[16];
    __shared__ int scnt;
    const int bucket = blockIdx.x;
    const int tid = threadIdx.x;
    if (tid < 16) lcur[tid] = 0;
    if (tid == 0) scnt = 0;
    __syncthreads();

#pragma unroll
    for (int xcd = 0; xcd < NXCD; xcd++) {
        int gb = (xcd << 8) | bucket;
        int cnt = gcur[gb];
        if (cnt > SEGCAP) cnt = SEGCAP;
        const u64* seg = bins + (size_t)gb * SEGCAP;
        for (int k = tid; k < cnt; k += 256) {
            u64 e = seg[k];
            int rl = (int)(e >> 12) & 15;
            int p = atomicAdd(&lcur[rl], 1);
            if (p < RCAP) lists[rl][p] = e;
            else { int s = atomicAdd(&scnt, 1); if (s < SCAP) stash[s] = e; }
        }
    }
    // rare global-overflow entries routed to this bucket
    int ovfn = *govf_cnt;
    if (ovfn > GOVFCAP) ovfn = GOVFCAP;
    for (int k = tid; k < ovfn; k += 256) {
        u64 e = govf[k];
        int rr = (int)(e >> 12) & 4095;
        if ((rr >> 4) == bucket) {
            u64 e2 = ((e >> 24) << 16) | (u64)((rr & 15) << 12) | (e & 4095);
            int rl = rr & 15;
            int p = atomicAdd(&lcur[rl], 1);
            if (p < RCAP) lists[rl][p] = e2;
            else { int s = atomicAdd(&scnt, 1); if (s < SCAP) stash[s] = e2; }
        }
    }
    __syncthreads();
    int sn = scnt > SCAP ? SCAP : scnt;

    for (int rl = 0; rl < 16; rl++) {
        // clear aux
#pragma unroll
        for (int j = 0; j < 4; j++) ((int4*)aux)[tid * 4 + j] = (int4){-1, -1, -1, -1};
        __syncthreads();
        int cnt = lcur[rl];
        if (cnt > RCAP) cnt = RCAP;
        for (int k = tid; k < cnt; k += 256) {
            u64 e = lists[rl][k];
            atomicMax(&aux[(int)(e & 4095)], (int)(e >> 16));
        }
        for (int k = tid; k < sn; k += 256) {
            u64 e = stash[k];
            if (((int)(e >> 12) & 15) == rl) atomicMax(&aux[(int)(e & 4095)], (int)(e >> 16));
        }
        __syncthreads();
        // emit row
        int rowg = (bucket << 4) | rl;
        int base = tid * 16;
        ushort4 o[4];
#pragma unroll
        for (int j = 0; j < 16; j++) {
            int a = aux[base + j];
            ((u16*)o)[j] = a >= 0 ? f2bf(w[a]) : (u16)0;
        }
        uint4* dst = (uint4*)(Wbf + (size_t)rowg * IN_F + base);
        dst[0] = ((const uint4*)o)[0];
        dst[1] = ((const uint4*)o)[1];
        __syncthreads();   // aux reuse
    }
}

__global__ __launch_bounds__(256) void conv_x(const float* __restrict__ x,
                                              u16* __restrict__ xbf) {
    int i = blockIdx.x * 256 + threadIdx.x;   // handles 4 elements
    float4 v = ((const float4*)x)[i];
    ushort4 o;
    o.x = f2bf(v.x); o.y = f2bf(v.y); o.z = f2bf(v.z); o.w = f2bf(v.w);
    ((ushort4*)xbf)[i] = o;
}

// C[m][n] = sum_k A[m][k]*B[n][k] + bias[n].  (unchanged from round 5)
__global__ __launch_bounds__(256) void gemm_bias(const u16* __restrict__ A,
                                                 const u16* __restrict__ B,
                                                 const float* __restrict__ bias,
                                                 float* __restrict__ C) {
    __shared__ u16 As[DEPTH][BM * BK];   // 4 x 8 KB
    __shared__ u16 Bs[DEPTH][BN * BK];   // 4 x 8 KB  => 64 KB
    const int L  = blockIdx.x;
    const int g  = L >> 3, xx = L & 7;
    const int m0 = (g >> 3) * BM;
    const int n0 = (xx + ((g & 7) << 3)) * BN;
    const int tid  = threadIdx.x;
    const int lane = tid & 63;
    const int wave = tid >> 6;
    const int wm = wave >> 1, wn = wave & 1;
    const int r15 = lane & 15, khi = lane >> 4;

    const u16* srcA[2]; const u16* srcB[2]; int dstO[2];
#pragma unroll
    for (int it = 0; it < 2; it++) {
        int o = tid * 16 + it * 4096;
        int rr = o >> 7, lblk = (o >> 4) & 7;
        srcA[it] = A + (size_t)(m0 + rr) * IN_F + ((lblk ^ (rr & 7)) << 3);
        srcB[it] = B + (size_t)(n0 + rr) * IN_F + ((lblk ^ (rr & 7)) << 3);
        dstO[it] = o >> 1;
    }

#define STAGE(slot, kt)                                                              \
    do {                                                                             \
        _Pragma("unroll")                                                            \
        for (int it = 0; it < 2; it++)                                               \
            __builtin_amdgcn_global_load_lds(                                        \
                (const __attribute__((address_space(1))) void*)(srcA[it] + (kt)),    \
                (__attribute__((address_space(3))) void*)(&As[slot][dstO[it]]),      \
                16, 0, 0);                                                           \
        _Pragma("unroll")                                                            \
        for (int it = 0; it < 2; it++)                                               \
            __builtin_amdgcn_global_load_lds(                                        \
                (const __attribute__((address_space(1))) void*)(srcB[it] + (kt)),    \
                (__attribute__((address_space(3))) void*)(&Bs[slot][dstO[it]]),      \
                16, 0, 0);                                                           \
    } while (0)

    f32x4 acc[2][2];
#pragma unroll
    for (int mi = 0; mi < 2; mi++)
#pragma unroll
        for (int nj = 0; nj < 2; nj++) acc[mi][nj] = (f32x4){0.f, 0.f, 0.f, 0.f};

    STAGE(0, 0); STAGE(1, BK); STAGE(2, 2 * BK);

    for (int t = 0; t < NSTEPS; ++t) {
        if (t < NSTEPS - 2)       asm volatile("s_waitcnt vmcnt(8)" ::: "memory");
        else if (t == NSTEPS - 2) asm volatile("s_waitcnt vmcnt(4)" ::: "memory");
        else                      asm volatile("s_waitcnt vmcnt(0)" ::: "memory");
        __builtin_amdgcn_s_barrier();
        __builtin_amdgcn_sched_barrier(0);
        if (t + 3 < NSTEPS) STAGE((t + 3) & 3, (t + 3) * BK);

        const char* as = (const char*)&As[t & 3][0];
        const char* bs = (const char*)&Bs[t & 3][0];
#pragma unroll
        for (int ks = 0; ks < 2; ks++) {
            bf16x8 a[2], b[2];
#pragma unroll
            for (int mi = 0; mi < 2; mi++) {
                int rowi = wm * 32 + mi * 16 + r15;
                a[mi] = *(const bf16x8*)(as + rowi * 128 + (((ks * 4 + khi) ^ (rowi & 7)) << 4));
            }
#pragma unroll
            for (int nj = 0; nj < 2; nj++) {
                int rowi = wn * 32 + nj * 16 + r15;
                b[nj] = *(const bf16x8*)(bs + rowi * 128 + (((ks * 4 + khi) ^ (rowi & 7)) << 4));
            }
#pragma unroll
            for (int mi = 0; mi < 2; mi++)
#pragma unroll
                for (int nj = 0; nj < 2; nj++)
                    acc[mi][nj] = __builtin_amdgcn_mfma_f32_16x16x32_bf16(a[mi], b[nj], acc[mi][nj], 0, 0, 0);
        }
    }
#undef STAGE

#pragma unroll
    for (int nj = 0; nj < 2; nj++) {
        int colg = n0 + wn * 32 + nj * 16 + r15;
        float bv = bias[colg];
#pragma unroll
        for (int mi = 0; mi < 2; mi++) {
#pragma unroll
            for (int j = 0; j < 4; j++) {
                int rowg = m0 + wm * 32 + mi * 16 + khi * 4 + j;
                C[(size_t)rowg * OUT_F + colg] = acc[mi][nj][j] + bv;
            }
        }
    }
}

extern "C" void kernel_launch(void* const* d_in, const int* in_sizes, int n_in,
                              void* d_out, int out_size, void* d_ws, size_t ws_size,
                              hipStream_t stream) {
    const float* x    = (const float*)d_in[0];
    const float* w1d  = (const float*)d_in[1];
    const float* bias = (const float*)d_in[2];
    const int*   row  = (const int*)d_in[3];
    const int*   col  = (const int*)d_in[4];
    const int nnz = in_sizes[1];

    char* ws       = (char*)d_ws;
    u64*  bins     = (u64*)ws;                             // 8*256*2048*8 = 32 MB [0,32)
    int*  gcur     = (int*)(ws + ((size_t)32 << 20));      // 8 KB
    int*  govf_cnt = gcur + NXCD * NB;                     // 4 B (right after gcur)
    u64*  govf     = (u64*)(ws + ((size_t)33 << 20));      // 16 MB [33,49)
    u16*  Wbf      = (u16*)(ws + ((size_t)64 << 20));      // 32 MB [64,96)
    u16*  xbf      = (u16*)(ws + ((size_t)96 << 20));      // 4 MB  [96,100)
    float* y       = (float*)d_out;

    conv_x<<<(BATCH * IN_F / 4) / 256, 256, 0, stream>>>(x, xbf);
    hipMemsetAsync(gcur, 0, (NXCD * NB + 1) * sizeof(int), stream);
    int nblk = (nnz + CHUNK - 1) / CHUNK;
    bucket_scatter<<<nblk, 256, 0, stream>>>(row, col, gcur, bins, govf_cnt, govf, nnz);
    build_w<<<NB, 256, 0, stream>>>(gcur, bins, govf_cnt, govf, w1d, Wbf);
    gemm_bias<<<8 * 64, 256, 0, stream>>>(xbf, Wbf, bias, y);
}

// Round 7
// 127.652 us; speedup vs baseline: 1.4236x; 1.4236x over previous
//
#include <hip/hip_runtime.h>
#include <hip/hip_bf16.h>

typedef unsigned short u16;
typedef unsigned long long u64;
typedef __attribute__((ext_vector_type(4))) float f32x4;
typedef __attribute__((ext_vector_type(8))) short bf16x8;

#define IN_F   4096
#define OUT_F  4096
#define BATCH  512

#define BM 64
#define BN 64
#define BK 64
#define NSTEPS (IN_F / BK)   // 64
#define DEPTH 4              // LDS ring, prefetch distance 3

#define NXCD    8
#define NB      256          // coarse buckets, 16 rows each
#define CHUNK   2048         // entries per bucket_scatter block
#define LCAP    24           // LDS bucket cap (mean 8, +5.6 sigma)
#define SEGCAP  2048         // per (xcd,bucket) seg cap (mean 781, +45 sigma)
#define GOVFCAP (2*1024*1024)

__device__ inline u16 f2bf(float f) {
    __hip_bfloat16 h = __float2bfloat16(f);   // RNE
    u16 u; __builtin_memcpy(&u, &h, 2); return u;
}

// Phase 1: LDS-aggregated coarse binning WITH WEIGHT INLINED.
// Round-6 lesson: the 1.6M random w[a] gathers in build (57MB of 64B-line
// misses) were the cost — but at scatter time i is SEQUENTIAL, so w[i] is a
// coalesced read. Entry: (i<<32)|(rl<<28)|(col<<16)|wbf.
// govf entry: (i<<40)|(row<<28)|(col<<16)|wbf.
__global__ __launch_bounds__(256) void bucket_scatter(const int* __restrict__ row,
                                                      const int* __restrict__ col,
                                                      const float* __restrict__ w,
                                                      int* __restrict__ gcur,
                                                      u64* __restrict__ bins,
                                                      int* __restrict__ govf_cnt,
                                                      u64* __restrict__ govf, int nnz) {
    __shared__ u64 lbin[NB][LCAP];   // 48 KB
    __shared__ int lcur[NB];
    const int xcd = __builtin_amdgcn_s_getreg(20 | (3 << 11)) & (NXCD - 1);
    const int tid = threadIdx.x;
    lcur[tid] = 0;
    __syncthreads();

    int base = blockIdx.x * CHUNK + tid * 8;
    if (base + 8 <= nnz) {
        int4 r0 = ((const int4*)(row + base))[0];
        int4 r1 = ((const int4*)(row + base))[1];
        int4 c0 = ((const int4*)(col + base))[0];
        int4 c1 = ((const int4*)(col + base))[1];
        float4 w0 = ((const float4*)(w + base))[0];
        float4 w1 = ((const float4*)(w + base))[1];
        int rs[8] = {r0.x, r0.y, r0.z, r0.w, r1.x, r1.y, r1.z, r1.w};
        int cs[8] = {c0.x, c0.y, c0.z, c0.w, c1.x, c1.y, c1.z, c1.w};
        float wsv[8] = {w0.x, w0.y, w0.z, w0.w, w1.x, w1.y, w1.z, w1.w};
#pragma unroll
        for (int j = 0; j < 8; j++) {
            int rr = rs[j], cc = cs[j], i = base + j;
            u64 wb = (u64)f2bf(wsv[j]);
            int bk = rr >> 4;
            int p = atomicAdd(&lcur[bk], 1);
            if (p < LCAP) {
                lbin[bk][p] = ((u64)i << 32) | ((u64)(rr & 15) << 28) | ((u64)cc << 16) | wb;
            } else {
                int o = atomicAdd(govf_cnt, 1);
                if (o < GOVFCAP) govf[o] = ((u64)i << 40) | ((u64)rr << 28) | ((u64)cc << 16) | wb;
            }
        }
    } else {
        int e = nnz < base + 8 ? nnz : base + 8;
        for (int i = base; i < e; i++) {
            int rr = row[i], cc = col[i];
            u64 wb = (u64)f2bf(w[i]);
            int bk = rr >> 4;
            int p = atomicAdd(&lcur[bk], 1);
            if (p < LCAP) {
                lbin[bk][p] = ((u64)i << 32) | ((u64)(rr & 15) << 28) | ((u64)cc << 16) | wb;
            } else {
                int o = atomicAdd(govf_cnt, 1);
                if (o < GOVFCAP) govf[o] = ((u64)i << 40) | ((u64)rr << 28) | ((u64)cc << 16) | wb;
            }
        }
    }
    __syncthreads();

    // flush: thread t owns bucket t; 1 global atomic per ~8 entries + contiguous stores
    int cnt = lcur[tid];
    if (cnt > LCAP) cnt = LCAP;
    if (cnt > 0) {
        int gb = (xcd << 8) | tid;
        int b0 = atomicAdd(&gcur[gb], cnt);
        u64* seg = bins + (size_t)gb * SEGCAP;
        for (int k = 0; k < cnt; k++) {
            u64 e = lbin[tid][k];
            int p = b0 + k;
            if (p < SEGCAP) {
                seg[p] = e;
            } else {
                int rr = (tid << 4) | ((int)(e >> 28) & 15);
                int o = atomicAdd(govf_cnt, 1);
                if (o < GOVFCAP) govf[o] = ((e >> 32) << 40) | ((u64)rr << 28) | (e & 0x0FFFFFFF);
            }
        }
    }
}

// Phase 2: ONE BLOCK PER ROW (4096 blocks, 32KB LDS -> 5 blocks/CU).
// Scan the owning bucket's 8 per-XCD segs (read-amplified 16x but L2-served;
// block->row mapping keeps all 16 sharers of a bucket on one XCD), filter by
// rl, resolve last-write-wins in ONE pass: atomicMax(aux[col], (i<<16)|wbf)
// — unique i makes max order-independent and carries the weight. Emit row.
__global__ __launch_bounds__(256) void build_row(const int* __restrict__ gcur,
                                                 const u64* __restrict__ bins,
                                                 const int* __restrict__ govf_cnt,
                                                 const u64* __restrict__ govf,
                                                 u16* __restrict__ Wbf) {
    __shared__ u64 aux[IN_F];   // 32 KB
    const int L   = blockIdx.x;
    const int rl  = (L >> 3) & 15;
    const int bucket = ((L >> 7) << 3) | (L & 7);   // bucket%8 == L%8 -> XCD-affine
    const int rowg = (bucket << 4) | rl;
    const int tid = threadIdx.x;

#pragma unroll
    for (int j = 0; j < IN_F / 256 / 2; j++)        // 8 u64-pairs = 16 u64 per thread
        ((ulonglong2*)aux)[tid * 8 + j] = (ulonglong2){0ull, 0ull};
    __syncthreads();

#pragma unroll
    for (int xcd = 0; xcd < NXCD; xcd++) {
        int gb = (xcd << 8) | bucket;
        int cnt = gcur[gb];
        if (cnt > SEGCAP) cnt = SEGCAP;
        const u64* seg = bins + (size_t)gb * SEGCAP;
        for (int k = tid; k < cnt; k += 256) {
            u64 e = seg[k];
            if (((int)(e >> 28) & 15) == rl)
                atomicMax(&aux[(int)(e >> 16) & 4095], ((e >> 32) << 16) | (e & 0xFFFF));
        }
    }
    // rare global-overflow entries
    int ovfn = *govf_cnt;
    if (ovfn > GOVFCAP) ovfn = GOVFCAP;
    for (int k = tid; k < ovfn; k += 256) {
        u64 e = govf[k];
        if (((int)(e >> 28) & 4095) == rowg)
            atomicMax(&aux[(int)(e >> 16) & 4095], ((e >> 40) << 16) | (e & 0xFFFF));
    }
    __syncthreads();

    // emit: 16 cols (32B) per thread
    int base = tid * 16;
    ushort4 o[4];
#pragma unroll
    for (int j = 0; j < 16; j++)
        ((u16*)o)[j] = (u16)(aux[base + j] & 0xFFFF);
    uint4* dst = (uint4*)(Wbf + (size_t)rowg * IN_F + base);
    dst[0] = ((const uint4*)o)[0];
    dst[1] = ((const uint4*)o)[1];
}

__global__ __launch_bounds__(256) void conv_x(const float* __restrict__ x,
                                              u16* __restrict__ xbf) {
    int i = blockIdx.x * 256 + threadIdx.x;   // handles 4 elements
    float4 v = ((const float4*)x)[i];
    ushort4 o;
    o.x = f2bf(v.x); o.y = f2bf(v.y); o.z = f2bf(v.z); o.w = f2bf(v.w);
    ((ushort4*)xbf)[i] = o;
}

// C[m][n] = sum_k A[m][k]*B[n][k] + bias[n].  (frozen since round 5)
__global__ __launch_bounds__(256) void gemm_bias(const u16* __restrict__ A,
                                                 const u16* __restrict__ B,
                                                 const float* __restrict__ bias,
                                                 float* __restrict__ C) {
    __shared__ u16 As[DEPTH][BM * BK];   // 4 x 8 KB
    __shared__ u16 Bs[DEPTH][BN * BK];   // 4 x 8 KB  => 64 KB
    const int L  = blockIdx.x;
    const int g  = L >> 3, xx = L & 7;
    const int m0 = (g >> 3) * BM;
    const int n0 = (xx + ((g & 7) << 3)) * BN;
    const int tid  = threadIdx.x;
    const int lane = tid & 63;
    const int wave = tid >> 6;
    const int wm = wave >> 1, wn = wave & 1;
    const int r15 = lane & 15, khi = lane >> 4;

    const u16* srcA[2]; const u16* srcB[2]; int dstO[2];
#pragma unroll
    for (int it = 0; it < 2; it++) {
        int o = tid * 16 + it * 4096;
        int rr = o >> 7, lblk = (o >> 4) & 7;
        srcA[it] = A + (size_t)(m0 + rr) * IN_F + ((lblk ^ (rr & 7)) << 3);
        srcB[it] = B + (size_t)(n0 + rr) * IN_F + ((lblk ^ (rr & 7)) << 3);
        dstO[it] = o >> 1;
    }

#define STAGE(slot, kt)                                                              \
    do {                                                                             \
        _Pragma("unroll")                                                            \
        for (int it = 0; it < 2; it++)                                               \
            __builtin_amdgcn_global_load_lds(                                        \
                (const __attribute__((address_space(1))) void*)(srcA[it] + (kt)),    \
                (__attribute__((address_space(3))) void*)(&As[slot][dstO[it]]),      \
                16, 0, 0);                                                           \
        _Pragma("unroll")                                                            \
        for (int it = 0; it < 2; it++)                                               \
            __builtin_amdgcn_global_load_lds(                                        \
                (const __attribute__((address_space(1))) void*)(srcB[it] + (kt)),    \
                (__attribute__((address_space(3))) void*)(&Bs[slot][dstO[it]]),      \
                16, 0, 0);                                                           \
    } while (0)

    f32x4 acc[2][2];
#pragma unroll
    for (int mi = 0; mi < 2; mi++)
#pragma unroll
        for (int nj = 0; nj < 2; nj++) acc[mi][nj] = (f32x4){0.f, 0.f, 0.f, 0.f};

    STAGE(0, 0); STAGE(1, BK); STAGE(2, 2 * BK);

    for (int t = 0; t < NSTEPS; ++t) {
        if (t < NSTEPS - 2)       asm volatile("s_waitcnt vmcnt(8)" ::: "memory");
        else if (t == NSTEPS - 2) asm volatile("s_waitcnt vmcnt(4)" ::: "memory");
        else                      asm volatile("s_waitcnt vmcnt(0)" ::: "memory");
        __builtin_amdgcn_s_barrier();
        __builtin_amdgcn_sched_barrier(0);
        if (t + 3 < NSTEPS) STAGE((t + 3) & 3, (t + 3) * BK);

        const char* as = (const char*)&As[t & 3][0];
        const char* bs = (const char*)&Bs[t & 3][0];
#pragma unroll
        for (int ks = 0; ks < 2; ks++) {
            bf16x8 a[2], b[2];
#pragma unroll
            for (int mi = 0; mi < 2; mi++) {
                int rowi = wm * 32 + mi * 16 + r15;
                a[mi] = *(const bf16x8*)(as + rowi * 128 + (((ks * 4 + khi) ^ (rowi & 7)) << 4));
            }
#pragma unroll
            for (int nj = 0; nj < 2; nj++) {
                int rowi = wn * 32 + nj * 16 + r15;
                b[nj] = *(const bf16x8*)(bs + rowi * 128 + (((ks * 4 + khi) ^ (rowi & 7)) << 4));
            }
#pragma unroll
            for (int mi = 0; mi < 2; mi++)
#pragma unroll
                for (int nj = 0; nj < 2; nj++)
                    acc[mi][nj] = __builtin_amdgcn_mfma_f32_16x16x32_bf16(a[mi], b[nj], acc[mi][nj], 0, 0, 0);
        }
    }
#undef STAGE

#pragma unroll
    for (int nj = 0; nj < 2; nj++) {
        int colg = n0 + wn * 32 + nj * 16 + r15;
        float bv = bias[colg];
#pragma unroll
        for (int mi = 0; mi < 2; mi++) {
#pragma unroll
            for (int j = 0; j < 4; j++) {
                int rowg = m0 + wm * 32 + mi * 16 + khi * 4 + j;
                C[(size_t)rowg * OUT_F + colg] = acc[mi][nj][j] + bv;
            }
        }
    }
}

extern "C" void kernel_launch(void* const* d_in, const int* in_sizes, int n_in,
                              void* d_out, int out_size, void* d_ws, size_t ws_size,
                              hipStream_t stream) {
    const float* x    = (const float*)d_in[0];
    const float* w1d  = (const float*)d_in[1];
    const float* bias = (const float*)d_in[2];
    const int*   row  = (const int*)d_in[3];
    const int*   col  = (const int*)d_in[4];
    const int nnz = in_sizes[1];

    char* ws       = (char*)d_ws;
    u64*  bins     = (u64*)ws;                             // 8*256*2048*8 = 32 MB [0,32)
    int*  gcur     = (int*)(ws + ((size_t)32 << 20));      // 8 KB
    int*  govf_cnt = gcur + NXCD * NB;                     // 4 B
    u64*  govf     = (u64*)(ws + ((size_t)33 << 20));      // 16 MB [33,49)
    u16*  Wbf      = (u16*)(ws + ((size_t)64 << 20));      // 32 MB [64,96)
    u16*  xbf      = (u16*)(ws + ((size_t)96 << 20));      // 4 MB  [96,100)
    float* y       = (float*)d_out;

    conv_x<<<(BATCH * IN_F / 4) / 256, 256, 0, stream>>>(x, xbf);
    hipMemsetAsync(gcur, 0, (NXCD * NB + 1) * sizeof(int), stream);
    int nblk = (nnz + CHUNK - 1) / CHUNK;
    bucket_scatter<<<nblk, 256, 0, stream>>>(row, col, w1d, gcur, bins, govf_cnt, govf, nnz);
    build_row<<<OUT_F, 256, 0, stream>>>(gcur, bins, govf_cnt, govf, Wbf);
    gemm_bias<<<8 * 64, 256, 0, stream>>>(xbf, Wbf, bias, y);
}

// Round 8
// 107.740 us; speedup vs baseline: 1.6867x; 1.1848x over previous
//
#include <hip/hip_runtime.h>
#include <hip/hip_bf16.h>

typedef unsigned short u16;
typedef unsigned long long u64;
typedef __attribute__((ext_vector_type(4))) float f32x4;
typedef __attribute__((ext_vector_type(8))) short bf16x8;

#define IN_F   4096
#define OUT_F  4096
#define BATCH  512

#define BM 128
#define BN 128
#define BK 64
#define KSPLIT 4
#define KC (IN_F / KSPLIT)     // 1024
#define NSTEPS (KC / BK)       // 16

#define NXCD    8
#define NB      256            // coarse buckets, 16 rows each
#define CHUNK   2048           // entries per bucket_scatter block
#define LCAP    24             // LDS bucket cap (mean 8, +5.6 sigma)
#define SEGCAP  2048           // per (xcd,bucket) seg cap
#define RCAP    640            // per-row list cap (mean 390, +12.7 sigma)
#define GOVFCAP (1024*1024)
#define OVF2CAP (128*1024)

__device__ inline u16 f2bf(float f) {
    __hip_bfloat16 h = __float2bfloat16(f);   // RNE
    u16 u; __builtin_memcpy(&u, &h, 2); return u;
}

// Phase 1: LDS-aggregated coarse binning, weight inlined (unchanged, ~10us).
// bin entry: (i<<32)|(rl<<28)|(col<<16)|wbf.  govf: (i<<40)|(row<<28)|(col<<16)|wbf.
__global__ __launch_bounds__(256) void bucket_scatter(const int* __restrict__ row,
                                                      const int* __restrict__ col,
                                                      const float* __restrict__ w,
                                                      int* __restrict__ gcur,
                                                      u64* __restrict__ bins,
                                                      int* __restrict__ govf_cnt,
                                                      u64* __restrict__ govf, int nnz) {
    __shared__ u64 lbin[NB][LCAP];   // 48 KB
    __shared__ int lcur[NB];
    const int xcd = __builtin_amdgcn_s_getreg(20 | (3 << 11)) & (NXCD - 1);
    const int tid = threadIdx.x;
    lcur[tid] = 0;
    __syncthreads();

    int base = blockIdx.x * CHUNK + tid * 8;
    if (base + 8 <= nnz) {
        int4 r0 = ((const int4*)(row + base))[0];
        int4 r1 = ((const int4*)(row + base))[1];
        int4 c0 = ((const int4*)(col + base))[0];
        int4 c1 = ((const int4*)(col + base))[1];
        float4 w0 = ((const float4*)(w + base))[0];
        float4 w1 = ((const float4*)(w + base))[1];
        int rs[8] = {r0.x, r0.y, r0.z, r0.w, r1.x, r1.y, r1.z, r1.w};
        int cs[8] = {c0.x, c0.y, c0.z, c0.w, c1.x, c1.y, c1.z, c1.w};
        float wsv[8] = {w0.x, w0.y, w0.z, w0.w, w1.x, w1.y, w1.z, w1.w};
#pragma unroll
        for (int j = 0; j < 8; j++) {
            int rr = rs[j], cc = cs[j], i = base + j;
            u64 wb = (u64)f2bf(wsv[j]);
            int bk = rr >> 4;
            int p = atomicAdd(&lcur[bk], 1);
            if (p < LCAP) {
                lbin[bk][p] = ((u64)i << 32) | ((u64)(rr & 15) << 28) | ((u64)cc << 16) | wb;
            } else {
                int o = atomicAdd(govf_cnt, 1);
                if (o < GOVFCAP) govf[o] = ((u64)i << 40) | ((u64)rr << 28) | ((u64)cc << 16) | wb;
            }
        }
    } else {
        int e = nnz < base + 8 ? nnz : base + 8;
        for (int i = base; i < e; i++) {
            int rr = row[i], cc = col[i];
            u64 wb = (u64)f2bf(w[i]);
            int bk = rr >> 4;
            int p = atomicAdd(&lcur[bk], 1);
            if (p < LCAP) {
                lbin[bk][p] = ((u64)i << 32) | ((u64)(rr & 15) << 28) | ((u64)cc << 16) | wb;
            } else {
                int o = atomicAdd(govf_cnt, 1);
                if (o < GOVFCAP) govf[o] = ((u64)i << 40) | ((u64)rr << 28) | ((u64)cc << 16) | wb;
            }
        }
    }
    __syncthreads();

    int cnt = lcur[tid];
    if (cnt > LCAP) cnt = LCAP;
    if (cnt > 0) {
        int gb = (xcd << 8) | tid;
        int b0 = atomicAdd(&gcur[gb], cnt);
        u64* seg = bins + (size_t)gb * SEGCAP;
        for (int k = 0; k < cnt; k++) {
            u64 e = lbin[tid][k];
            int p = b0 + k;
            if (p < SEGCAP) {
                seg[p] = e;
            } else {
                int rr = (tid << 4) | ((int)(e >> 28) & 15);
                int o = atomicAdd(govf_cnt, 1);
                if (o < GOVFCAP) govf[o] = ((e >> 32) << 40) | ((u64)rr << 28) | (e & 0x0FFFFFFF);
            }
        }
    }
}

// Phase 2a: one block per bucket. Read the 8 segs ONCE (round-7 lesson: the
// 16x filtered re-scan was the 58us), route to 16 per-row LDS lists, flush
// each list contiguously to rowbins. Overflow -> ovf2 (govf format).
__global__ __launch_bounds__(256) void split_bucket(const int* __restrict__ gcur,
                                                    const u64* __restrict__ bins,
                                                    const int* __restrict__ govf_cnt,
                                                    const u64* __restrict__ govf,
                                                    u64* __restrict__ rowbins,
                                                    int* __restrict__ rowcnt,
                                                    int* __restrict__ ovf2_cnt,
                                                    u64* __restrict__ ovf2) {
    __shared__ u64 lists[16][RCAP];   // 80 KB
    __shared__ int lcur[16];
    const int bucket = blockIdx.x;
    const int tid = threadIdx.x;
    if (tid < 16) lcur[tid] = 0;
    __syncthreads();

#pragma unroll
    for (int xcd = 0; xcd < NXCD; xcd++) {
        int gb = (xcd << 8) | bucket;
        int cnt = gcur[gb];
        if (cnt > SEGCAP) cnt = SEGCAP;
        const u64* seg = bins + (size_t)gb * SEGCAP;
        for (int k = tid; k < cnt; k += 256) {
            u64 e = seg[k];
            int rl = (int)(e >> 28) & 15;
            int p = atomicAdd(&lcur[rl], 1);
            if (p < RCAP) lists[rl][p] = e;
            else {
                int rr = (bucket << 4) | rl;
                int o = atomicAdd(ovf2_cnt, 1);
                if (o < OVF2CAP) ovf2[o] = ((e >> 32) << 40) | ((u64)rr << 28) | (e & 0x0FFFFFFF);
            }
        }
    }
    // route rare govf entries belonging to this bucket
    int ovfn = *govf_cnt;
    if (ovfn > GOVFCAP) ovfn = GOVFCAP;
    for (int k = tid; k < ovfn; k += 256) {
        u64 e = govf[k];
        int rr = (int)(e >> 28) & 4095;
        if ((rr >> 4) == bucket) {
            u64 e2 = ((e >> 40) << 32) | ((u64)(rr & 15) << 28) | (e & 0x0FFFFFFF);
            int rl = rr & 15;
            int p = atomicAdd(&lcur[rl], 1);
            if (p < RCAP) lists[rl][p] = e2;
            else { int o = atomicAdd(ovf2_cnt, 1); if (o < OVF2CAP) ovf2[o] = ((e2 >> 32) << 40) | ((u64)rr << 28) | (e2 & 0x0FFFFFFF); }
        }
    }
    __syncthreads();

    // flush: coalesced contiguous runs per row
    for (int rl = 0; rl < 16; rl++) {
        int cnt = lcur[rl];
        if (cnt > RCAP) cnt = RCAP;
        int rowg = (bucket << 4) | rl;
        u64* dst = rowbins + (size_t)rowg * RCAP;
        for (int k = tid; k < cnt; k += 256) dst[k] = lists[rl][k];
        if (tid == 0) rowcnt[rowg] = cnt;
    }
}

// Phase 2b: one block per row (32KB LDS -> 5 blocks/CU). Read ONLY this row's
// ~390 entries, resolve last-write-wins via atomicMax(aux[col], (i<<16)|wbf)
// (unique i => order-independent, weight rides along), emit coalesced.
__global__ __launch_bounds__(256) void build_row2(const u64* __restrict__ rowbins,
                                                  const int* __restrict__ rowcnt,
                                                  const int* __restrict__ ovf2_cnt,
                                                  const u64* __restrict__ ovf2,
                                                  u16* __restrict__ Wbf) {
    __shared__ u64 aux[IN_F];   // 32 KB
    const int rowg = blockIdx.x;
    const int tid = threadIdx.x;

#pragma unroll
    for (int j = 0; j < IN_F / 256 / 2; j++)
        ((ulonglong2*)aux)[tid * 8 + j] = (ulonglong2){0ull, 0ull};
    __syncthreads();

    int cnt = rowcnt[rowg];
    const u64* seg = rowbins + (size_t)rowg * RCAP;
    for (int k = tid; k < cnt; k += 256) {
        u64 e = seg[k];
        atomicMax(&aux[(int)(e >> 16) & 4095], ((e >> 32) << 16) | (e & 0xFFFF));
    }
    int o2 = *ovf2_cnt;
    if (o2 > OVF2CAP) o2 = OVF2CAP;
    for (int k = tid; k < o2; k += 256) {
        u64 e = ovf2[k];
        if (((int)(e >> 28) & 4095) == rowg)
            atomicMax(&aux[(int)(e >> 16) & 4095], ((e >> 40) << 16) | (e & 0xFFFF));
    }
    __syncthreads();

    int base = tid * 16;
    ushort4 o[4];
#pragma unroll
    for (int j = 0; j < 16; j++)
        ((u16*)o)[j] = (u16)(aux[base + j] & 0xFFFF);
    uint4* dst = (uint4*)(Wbf + (size_t)rowg * IN_F + base);
    dst[0] = ((const uint4*)o)[0];
    dst[1] = ((const uint4*)o)[1];
}

__global__ __launch_bounds__(256) void conv_x(const float* __restrict__ x,
                                              u16* __restrict__ xbf) {
    int i = blockIdx.x * 256 + threadIdx.x;
    float4 v = ((const float4*)x)[i];
    ushort4 o;
    o.x = f2bf(v.x); o.y = f2bf(v.y); o.z = f2bf(v.z); o.w = f2bf(v.w);
    ((ushort4*)xbf)[i] = o;
}

// Partial GEMM, m93 geometry: 128x128 tile, 4 waves, wave-tile 64x64, acc 4x4
// (32 MFMA : 16 ds_read_b128 per K-step — round-7 ratio fix vs 64x64's 1:1).
// KSPLIT=4 -> 512 blocks = 2/CU. T3-minimum 2-phase: STAGE(next) first, one
// vmcnt(0)+barrier per K-step. Source-side XOR swizzle (verified r5-r7).
__global__ __launch_bounds__(256) void gemm_part(const u16* __restrict__ A,
                                                 const u16* __restrict__ B,
                                                 float* __restrict__ part) {
    __shared__ u16 As[2][BM * BK];   // 2 x 16 KB
    __shared__ u16 Bs[2][BN * BK];   // 2 x 16 KB => 64 KB
    const int L   = blockIdx.x;
    const int xx  = L & 7;
    const int rst = L >> 3;
    const int m   = rst & 3;                  // 4 M-blocks
    const int g   = ((rst >> 2) << 3) | xx;   // 128 groups (n,kc); g%8==L%8 -> XCD-affine B panel
    const int n   = g & 31;                   // 32 N-blocks
    const int kc  = g >> 5;                   // 4 K-chunks
    const int m0  = m * BM;
    const int n0  = n * BN;
    const int kt0 = kc * KC;

    const int tid  = threadIdx.x;
    const int lane = tid & 63;
    const int wave = tid >> 6;
    const int wm = wave >> 1, wn = wave & 1;   // 2x2 waves, wave tile 64x64
    const int r15 = lane & 15, khi = lane >> 4;

    // staging: 16KB per tile, 4 x 16B issues per thread; source pre-XOR'd
    const u16* srcA[4]; const u16* srcB[4]; int dstO[4];
#pragma unroll
    for (int it = 0; it < 4; it++) {
        int o = tid * 16 + it * 4096;
        int rr = o >> 7, lblk = (o >> 4) & 7;
        srcA[it] = A + (size_t)(m0 + rr) * IN_F + kt0 + ((lblk ^ (rr & 7)) << 3);
        srcB[it] = B + (size_t)(n0 + rr) * IN_F + kt0 + ((lblk ^ (rr & 7)) << 3);
        dstO[it] = o >> 1;
    }

#define STAGE(buf, kk)                                                               \
    do {                                                                             \
        _Pragma("unroll")                                                            \
        for (int it = 0; it < 4; it++)                                               \
            __builtin_amdgcn_global_load_lds(                                        \
                (const __attribute__((address_space(1))) void*)(srcA[it] + (kk)),    \
                (__attribute__((address_space(3))) void*)(&As[buf][dstO[it]]),       \
                16, 0, 0);                                                           \
        _Pragma("unroll")                                                            \
        for (int it = 0; it < 4; it++)                                               \
            __builtin_amdgcn_global_load_lds(                                        \
                (const __attribute__((address_space(1))) void*)(srcB[it] + (kk)),    \
                (__attribute__((address_space(3))) void*)(&Bs[buf][dstO[it]]),       \
                16, 0, 0);                                                           \
    } while (0)

    f32x4 acc[4][4];
#pragma unroll
    for (int mi = 0; mi < 4; mi++)
#pragma unroll
        for (int nj = 0; nj < 4; nj++) acc[mi][nj] = (f32x4){0.f, 0.f, 0.f, 0.f};

    STAGE(0, 0);
    asm volatile("s_waitcnt vmcnt(0)" ::: "memory");
    __builtin_amdgcn_s_barrier();

    for (int t = 0; t < NSTEPS; ++t) {
        const int cur = t & 1;
        if (t + 1 < NSTEPS) STAGE(cur ^ 1, (t + 1) * BK);   // issue next first

        const char* as = (const char*)&As[cur][0];
        const char* bs = (const char*)&Bs[cur][0];
#pragma unroll
        for (int ks = 0; ks < 2; ks++) {
            bf16x8 a[4], b[4];
#pragma unroll
            for (int mi = 0; mi < 4; mi++) {
                int rowi = wm * 64 + mi * 16 + r15;
                a[mi] = *(const bf16x8*)(as + rowi * 128 + (((ks * 4 + khi) ^ (rowi & 7)) << 4));
            }
#pragma unroll
            for (int nj = 0; nj < 4; nj++) {
                int rowi = wn * 64 + nj * 16 + r15;
                b[nj] = *(const bf16x8*)(bs + rowi * 128 + (((ks * 4 + khi) ^ (rowi & 7)) << 4));
            }
#pragma unroll
            for (int mi = 0; mi < 4; mi++)
#pragma unroll
                for (int nj = 0; nj < 4; nj++)
                    acc[mi][nj] = __builtin_amdgcn_mfma_f32_16x16x32_bf16(a[mi], b[nj], acc[mi][nj], 0, 0, 0);
        }
        asm volatile("s_waitcnt vmcnt(0)" ::: "memory");   // next tile landed
        __builtin_amdgcn_s_barrier();                      // all waves done reading cur
    }
#undef STAGE

    float* P = part + (size_t)kc * BATCH * OUT_F;
#pragma unroll
    for (int nj = 0; nj < 4; nj++) {
        int colg = n0 + wn * 64 + nj * 16 + r15;
#pragma unroll
        for (int mi = 0; mi < 4; mi++) {
#pragma unroll
            for (int j = 0; j < 4; j++) {
                int rowg = m0 + wm * 64 + mi * 16 + khi * 4 + j;
                P[(size_t)rowg * OUT_F + colg] = acc[mi][nj][j];
            }
        }
    }
}

// y = sum_kc part[kc] + bias
__global__ __launch_bounds__(256) void reduce_bias(const float* __restrict__ part,
                                                   const float* __restrict__ bias,
                                                   float* __restrict__ y) {
    int i = blockIdx.x * 256 + threadIdx.x;          // f32x4 index
    const size_t STRIDE = (size_t)BATCH * OUT_F / 4;
    f32x4 s = ((const f32x4*)part)[i];
#pragma unroll
    for (int k = 1; k < KSPLIT; k++) s += ((const f32x4*)part)[i + k * STRIDE];
    int col4 = (i * 4) & (OUT_F - 1);
    f32x4 b = *(const f32x4*)&bias[col4];
    ((f32x4*)y)[i] = s + b;
}

extern "C" void kernel_launch(void* const* d_in, const int* in_sizes, int n_in,
                              void* d_out, int out_size, void* d_ws, size_t ws_size,
                              hipStream_t stream) {
    const float* x    = (const float*)d_in[0];
    const float* w1d  = (const float*)d_in[1];
    const float* bias = (const float*)d_in[2];
    const int*   row  = (const int*)d_in[3];
    const int*   col  = (const int*)d_in[4];
    const int nnz = in_sizes[1];

    char* ws        = (char*)d_ws;
    u64*  bins      = (u64*)ws;                             // 32 MB [0,32) — dead after split_bucket
    float* part     = (float*)ws;                           // 32 MB [0,32) — overlays bins (gemm partials)
    int*  gcur      = (int*)(ws + ((size_t)32 << 20));      // 8 KB
    int*  govf_cnt  = gcur + NXCD * NB;
    int*  ovf2_cnt  = govf_cnt + 1;
    u64*  govf      = (u64*)(ws + ((size_t)33 << 20));      // 8 MB  [33,41)
    u64*  rowbins   = (u64*)(ws + ((size_t)41 << 20));      // 20 MB [41,61)
    int*  rowcnt    = (int*)(ws + ((size_t)61 << 20));      // 16 KB
    u64*  ovf2      = (u64*)(ws + ((size_t)62 << 20));      // 1 MB  [62,63)
    u16*  Wbf       = (u16*)(ws + ((size_t)64 << 20));      // 32 MB [64,96)
    u16*  xbf       = (u16*)(ws + ((size_t)96 << 20));      // 4 MB  [96,100)
    float* y        = (float*)d_out;

    conv_x<<<(BATCH * IN_F / 4) / 256, 256, 0, stream>>>(x, xbf);
    hipMemsetAsync(gcur, 0, (NXCD * NB + 2) * sizeof(int), stream);
    int nblk = (nnz + CHUNK - 1) / CHUNK;
    bucket_scatter<<<nblk, 256, 0, stream>>>(row, col, w1d, gcur, bins, govf_cnt, govf, nnz);
    split_bucket<<<NB, 256, 0, stream>>>(gcur, bins, govf_cnt, govf, rowbins, rowcnt, ovf2_cnt, ovf2);
    build_row2<<<OUT_F, 256, 0, stream>>>(rowbins, rowcnt, ovf2_cnt, ovf2, Wbf);
    gemm_part<<<512, 256, 0, stream>>>(xbf, Wbf, part);
    reduce_bias<<<(BATCH * OUT_F / 4) / 256, 256, 0, stream>>>(part, bias, y);
}

// Round 9
// 103.431 us; speedup vs baseline: 1.7570x; 1.0417x over previous
//
#include <hip/hip_runtime.h>
#include <hip/hip_bf16.h>

typedef unsigned short u16;
typedef unsigned long long u64;
typedef __attribute__((ext_vector_type(4))) float f32x4;
typedef __attribute__((ext_vector_type(8))) short bf16x8;

#define IN_F   4096
#define OUT_F  4096
#define BATCH  512

#define BM 128
#define BN 128
#define BK 64
#define KSPLIT 4
#define KC (IN_F / KSPLIT)     // 1024
#define NSTEPS (KC / BK)       // 16

#define NXCD    8
#define NB      256            // coarse buckets, 16 rows each
#define CHUNK   2048           // entries per bucket_scatter block
#define LCAP    24             // LDS bucket cap (mean 8, +5.6 sigma)
#define SEGCAP  2048           // per (xcd,bucket) seg cap
#define RCAP    640            // per-row list cap (mean 390, +12.7 sigma)
#define GOVFCAP (1024*1024)
#define OVF2CAP (128*1024)
#define NCTR    (NXCD * NB + 2)   // gcur + govf_cnt + ovf2_cnt

__device__ inline u16 f2bf(float f) {
    __hip_bfloat16 h = __float2bfloat16(f);   // RNE
    u16 u; __builtin_memcpy(&u, &h, 2); return u;
}

// conv_x + counter clear (round-9: the in-graph 8KB hipMemsetAsync showed up
// as a ~40us fillBufferAligned dispatch — clear the counters ourselves).
__global__ __launch_bounds__(256) void conv_x(const float* __restrict__ x,
                                              u16* __restrict__ xbf,
                                              int* __restrict__ ctrs) {
    const int tid = threadIdx.x;
    if (blockIdx.x == 0) {
        for (int j = tid; j < NCTR; j += 256) ctrs[j] = 0;
    }
    int i = blockIdx.x * 256 + tid;
    float4 v = ((const float4*)x)[i];
    ushort4 o;
    o.x = f2bf(v.x); o.y = f2bf(v.y); o.z = f2bf(v.z); o.w = f2bf(v.w);
    ((ushort4*)xbf)[i] = o;
}

// Phase 1: LDS-aggregated coarse binning, weight inlined.
// bin entry: (i<<32)|(rl<<28)|(col<<16)|wbf.  govf: (i<<40)|(row<<28)|(col<<16)|wbf.
__global__ __launch_bounds__(256) void bucket_scatter(const int* __restrict__ row,
                                                      const int* __restrict__ col,
                                                      const float* __restrict__ w,
                                                      int* __restrict__ gcur,
                                                      u64* __restrict__ bins,
                                                      int* __restrict__ govf_cnt,
                                                      u64* __restrict__ govf, int nnz) {
    __shared__ u64 lbin[NB][LCAP];   // 48 KB
    __shared__ int lcur[NB];
    const int xcd = __builtin_amdgcn_s_getreg(20 | (3 << 11)) & (NXCD - 1);
    const int tid = threadIdx.x;
    lcur[tid] = 0;
    __syncthreads();

    int base = blockIdx.x * CHUNK + tid * 8;
    if (base + 8 <= nnz) {
        int4 r0 = ((const int4*)(row + base))[0];
        int4 r1 = ((const int4*)(row + base))[1];
        int4 c0 = ((const int4*)(col + base))[0];
        int4 c1 = ((const int4*)(col + base))[1];
        float4 w0 = ((const float4*)(w + base))[0];
        float4 w1 = ((const float4*)(w + base))[1];
        int rs[8] = {r0.x, r0.y, r0.z, r0.w, r1.x, r1.y, r1.z, r1.w};
        int cs[8] = {c0.x, c0.y, c0.z, c0.w, c1.x, c1.y, c1.z, c1.w};
        float wsv[8] = {w0.x, w0.y, w0.z, w0.w, w1.x, w1.y, w1.z, w1.w};
#pragma unroll
        for (int j = 0; j < 8; j++) {
            int rr = rs[j], cc = cs[j], i = base + j;
            u64 wb = (u64)f2bf(wsv[j]);
            int bk = rr >> 4;
            int p = atomicAdd(&lcur[bk], 1);
            if (p < LCAP) {
                lbin[bk][p] = ((u64)i << 32) | ((u64)(rr & 15) << 28) | ((u64)cc << 16) | wb;
            } else {
                int o = atomicAdd(govf_cnt, 1);
                if (o < GOVFCAP) govf[o] = ((u64)i << 40) | ((u64)rr << 28) | ((u64)cc << 16) | wb;
            }
        }
    } else {
        int e = nnz < base + 8 ? nnz : base + 8;
        for (int i = base; i < e; i++) {
            int rr = row[i], cc = col[i];
            u64 wb = (u64)f2bf(w[i]);
            int bk = rr >> 4;
            int p = atomicAdd(&lcur[bk], 1);
            if (p < LCAP) {
                lbin[bk][p] = ((u64)i << 32) | ((u64)(rr & 15) << 28) | ((u64)cc << 16) | wb;
            } else {
                int o = atomicAdd(govf_cnt, 1);
                if (o < GOVFCAP) govf[o] = ((u64)i << 40) | ((u64)rr << 28) | ((u64)cc << 16) | wb;
            }
        }
    }
    __syncthreads();

    int cnt = lcur[tid];
    if (cnt > LCAP) cnt = LCAP;
    if (cnt > 0) {
        int gb = (xcd << 8) | tid;
        int b0 = atomicAdd(&gcur[gb], cnt);
        u64* seg = bins + (size_t)gb * SEGCAP;
        for (int k = 0; k < cnt; k++) {
            u64 e = lbin[tid][k];
            int p = b0 + k;
            if (p < SEGCAP) {
                seg[p] = e;
            } else {
                int rr = (tid << 4) | ((int)(e >> 28) & 15);
                int o = atomicAdd(govf_cnt, 1);
                if (o < GOVFCAP) govf[o] = ((e >> 32) << 40) | ((u64)rr << 28) | (e & 0x0FFFFFFF);
            }
        }
    }
}

// Phase 2a: one block per bucket. Read the 8 segs ONCE, route to 16 per-row
// LDS lists, flush each contiguously to rowbins. Overflow -> ovf2.
__global__ __launch_bounds__(256) void split_bucket(const int* __restrict__ gcur,
                                                    const u64* __restrict__ bins,
                                                    const int* __restrict__ govf_cnt,
                                                    const u64* __restrict__ govf,
                                                    u64* __restrict__ rowbins,
                                                    int* __restrict__ rowcnt,
                                                    int* __restrict__ ovf2_cnt,
                                                    u64* __restrict__ ovf2) {
    __shared__ u64 lists[16][RCAP];   // 80 KB
    __shared__ int lcur[16];
    const int bucket = blockIdx.x;
    const int tid = threadIdx.x;
    if (tid < 16) lcur[tid] = 0;
    __syncthreads();

#pragma unroll
    for (int xcd = 0; xcd < NXCD; xcd++) {
        int gb = (xcd << 8) | bucket;
        int cnt = gcur[gb];
        if (cnt > SEGCAP) cnt = SEGCAP;
        const u64* seg = bins + (size_t)gb * SEGCAP;
        for (int k = tid; k < cnt; k += 256) {
            u64 e = seg[k];
            int rl = (int)(e >> 28) & 15;
            int p = atomicAdd(&lcur[rl], 1);
            if (p < RCAP) lists[rl][p] = e;
            else {
                int rr = (bucket << 4) | rl;
                int o = atomicAdd(ovf2_cnt, 1);
                if (o < OVF2CAP) ovf2[o] = ((e >> 32) << 40) | ((u64)rr << 28) | (e & 0x0FFFFFFF);
            }
        }
    }
    int ovfn = *govf_cnt;
    if (ovfn > GOVFCAP) ovfn = GOVFCAP;
    for (int k = tid; k < ovfn; k += 256) {
        u64 e = govf[k];
        int rr = (int)(e >> 28) & 4095;
        if ((rr >> 4) == bucket) {
            u64 e2 = ((e >> 40) << 32) | ((u64)(rr & 15) << 28) | (e & 0x0FFFFFFF);
            int rl = rr & 15;
            int p = atomicAdd(&lcur[rl], 1);
            if (p < RCAP) lists[rl][p] = e2;
            else { int o = atomicAdd(ovf2_cnt, 1); if (o < OVF2CAP) ovf2[o] = ((e2 >> 32) << 40) | ((u64)rr << 28) | (e2 & 0x0FFFFFFF); }
        }
    }
    __syncthreads();

    for (int rl = 0; rl < 16; rl++) {
        int cnt = lcur[rl];
        if (cnt > RCAP) cnt = RCAP;
        int rowg = (bucket << 4) | rl;
        u64* dst = rowbins + (size_t)rowg * RCAP;
        for (int k = tid; k < cnt; k += 256) dst[k] = lists[rl][k];
        if (tid == 0) rowcnt[rowg] = cnt;
    }
}

// Phase 2b: one block per row. Resolve last-write-wins via
// atomicMax(aux[col], (i<<16)|wbf) — unique i => order-independent. Emit row.
__global__ __launch_bounds__(256) void build_row2(const u64* __restrict__ rowbins,
                                                  const int* __restrict__ rowcnt,
                                                  const int* __restrict__ ovf2_cnt,
                                                  const u64* __restrict__ ovf2,
                                                  u16* __restrict__ Wbf) {
    __shared__ u64 aux[IN_F];   // 32 KB
    const int rowg = blockIdx.x;
    const int tid = threadIdx.x;

#pragma unroll
    for (int j = 0; j < IN_F / 256 / 2; j++)
        ((ulonglong2*)aux)[tid * 8 + j] = (ulonglong2){0ull, 0ull};
    __syncthreads();

    int cnt = rowcnt[rowg];
    const u64* seg = rowbins + (size_t)rowg * RCAP;
    for (int k = tid; k < cnt; k += 256) {
        u64 e = seg[k];
        atomicMax(&aux[(int)(e >> 16) & 4095], ((e >> 32) << 16) | (e & 0xFFFF));
    }
    int o2 = *ovf2_cnt;
    if (o2 > OVF2CAP) o2 = OVF2CAP;
    for (int k = tid; k < o2; k += 256) {
        u64 e = ovf2[k];
        if (((int)(e >> 28) & 4095) == rowg)
            atomicMax(&aux[(int)(e >> 16) & 4095], ((e >> 40) << 16) | (e & 0xFFFF));
    }
    __syncthreads();

    int base = tid * 16;
    ushort4 o[4];
#pragma unroll
    for (int j = 0; j < 16; j++)
        ((u16*)o)[j] = (u16)(aux[base + j] & 0xFFFF);
    uint4* dst = (uint4*)(Wbf + (size_t)rowg * IN_F + base);
    dst[0] = ((const uint4*)o)[0];
    dst[1] = ((const uint4*)o)[1];
}

// Partial GEMM, 128x128 tile, 4 waves (wave-tile 64x64, acc 4x4, 32 MFMA :
// 16 ds_read per K-step). KSPLIT=4 -> 512 blocks = 2/CU. 2-phase dbuf:
// STAGE(next) first, one vmcnt(0)+barrier per K-step. Source-XOR swizzle.
// (frozen from round 8)
__global__ __launch_bounds__(256) void gemm_part(const u16* __restrict__ A,
                                                 const u16* __restrict__ B,
                                                 float* __restrict__ part) {
    __shared__ u16 As[2][BM * BK];   // 2 x 16 KB
    __shared__ u16 Bs[2][BN * BK];   // 2 x 16 KB => 64 KB
    const int L   = blockIdx.x;
    const int xx  = L & 7;
    const int rst = L >> 3;
    const int m   = rst & 3;
    const int g   = ((rst >> 2) << 3) | xx;   // g%8==L%8 -> XCD-affine B panel
    const int n   = g & 31;
    const int kc  = g >> 5;
    const int m0  = m * BM;
    const int n0  = n * BN;
    const int kt0 = kc * KC;

    const int tid  = threadIdx.x;
    const int lane = tid & 63;
    const int wave = tid >> 6;
    const int wm = wave >> 1, wn = wave & 1;   // 2x2 waves, wave tile 64x64
    const int r15 = lane & 15, khi = lane >> 4;

    const u16* srcA[4]; const u16* srcB[4]; int dstO[4];
#pragma unroll
    for (int it = 0; it < 4; it++) {
        int o = tid * 16 + it * 4096;
        int rr = o >> 7, lblk = (o >> 4) & 7;
        srcA[it] = A + (size_t)(m0 + rr) * IN_F + kt0 + ((lblk ^ (rr & 7)) << 3);
        srcB[it] = B + (size_t)(n0 + rr) * IN_F + kt0 + ((lblk ^ (rr & 7)) << 3);
        dstO[it] = o >> 1;
    }

#define STAGE(buf, kk)                                                               \
    do {                                                                             \
        _Pragma("unroll")                                                            \
        for (int it = 0; it < 4; it++)                                               \
            __builtin_amdgcn_global_load_lds(                                        \
                (const __attribute__((address_space(1))) void*)(srcA[it] + (kk)),    \
                (__attribute__((address_space(3))) void*)(&As[buf][dstO[it]]),       \
                16, 0, 0);                                                           \
        _Pragma("unroll")                                                            \
        for (int it = 0; it < 4; it++)                                               \
            __builtin_amdgcn_global_load_lds(                                        \
                (const __attribute__((address_space(1))) void*)(srcB[it] + (kk)),    \
                (__attribute__((address_space(3))) void*)(&Bs[buf][dstO[it]]),       \
                16, 0, 0);                                                           \
    } while (0)

    f32x4 acc[4][4];
#pragma unroll
    for (int mi = 0; mi < 4; mi++)
#pragma unroll
        for (int nj = 0; nj < 4; nj++) acc[mi][nj] = (f32x4){0.f, 0.f, 0.f, 0.f};

    STAGE(0, 0);
    asm volatile("s_waitcnt vmcnt(0)" ::: "memory");
    __builtin_amdgcn_s_barrier();

    for (int t = 0; t < NSTEPS; ++t) {
        const int cur = t & 1;
        if (t + 1 < NSTEPS) STAGE(cur ^ 1, (t + 1) * BK);

        const char* as = (const char*)&As[cur][0];
        const char* bs = (const char*)&Bs[cur][0];
#pragma unroll
        for (int ks = 0; ks < 2; ks++) {
            bf16x8 a[4], b[4];
#pragma unroll
            for (int mi = 0; mi < 4; mi++) {
                int rowi = wm * 64 + mi * 16 + r15;
                a[mi] = *(const bf16x8*)(as + rowi * 128 + (((ks * 4 + khi) ^ (rowi & 7)) << 4));
            }
#pragma unroll
            for (int nj = 0; nj < 4; nj++) {
                int rowi = wn * 64 + nj * 16 + r15;
                b[nj] = *(const bf16x8*)(bs + rowi * 128 + (((ks * 4 + khi) ^ (rowi & 7)) << 4));
            }
#pragma unroll
            for (int mi = 0; mi < 4; mi++)
#pragma unroll
                for (int nj = 0; nj < 4; nj++)
                    acc[mi][nj] = __builtin_amdgcn_mfma_f32_16x16x32_bf16(a[mi], b[nj], acc[mi][nj], 0, 0, 0);
        }
        asm volatile("s_waitcnt vmcnt(0)" ::: "memory");
        __builtin_amdgcn_s_barrier();
    }
#undef STAGE

    float* P = part + (size_t)kc * BATCH * OUT_F;
#pragma unroll
    for (int nj = 0; nj < 4; nj++) {
        int colg = n0 + wn * 64 + nj * 16 + r15;
#pragma unroll
        for (int mi = 0; mi < 4; mi++) {
#pragma unroll
            for (int j = 0; j < 4; j++) {
                int rowg = m0 + wm * 64 + mi * 16 + khi * 4 + j;
                P[(size_t)rowg * OUT_F + colg] = acc[mi][nj][j];
            }
        }
    }
}

// y = sum_kc part[kc] + bias
__global__ __launch_bounds__(256) void reduce_bias(const float* __restrict__ part,
                                                   const float* __restrict__ bias,
                                                   float* __restrict__ y) {
    int i = blockIdx.x * 256 + threadIdx.x;
    const size_t STRIDE = (size_t)BATCH * OUT_F / 4;
    f32x4 s = ((const f32x4*)part)[i];
#pragma unroll
    for (int k = 1; k < KSPLIT; k++) s += ((const f32x4*)part)[i + k * STRIDE];
    int col4 = (i * 4) & (OUT_F - 1);
    f32x4 b = *(const f32x4*)&bias[col4];
    ((f32x4*)y)[i] = s + b;
}

extern "C" void kernel_launch(void* const* d_in, const int* in_sizes, int n_in,
                              void* d_out, int out_size, void* d_ws, size_t ws_size,
                              hipStream_t stream) {
    const float* x    = (const float*)d_in[0];
    const float* w1d  = (const float*)d_in[1];
    const float* bias = (const float*)d_in[2];
    const int*   row  = (const int*)d_in[3];
    const int*   col  = (const int*)d_in[4];
    const int nnz = in_sizes[1];

    char* ws        = (char*)d_ws;
    u64*  bins      = (u64*)ws;                             // 32 MB [0,32) — dead after split_bucket
    float* part     = (float*)ws;                           // 32 MB [0,32) — overlays bins
    int*  gcur      = (int*)(ws + ((size_t)32 << 20));      // 8 KB (+2 cnts = NCTR ints)
    int*  govf_cnt  = gcur + NXCD * NB;
    int*  ovf2_cnt  = govf_cnt + 1;
    u64*  govf      = (u64*)(ws + ((size_t)33 << 20));      // 8 MB  [33,41)
    u64*  rowbins   = (u64*)(ws + ((size_t)41 << 20));      // 20 MB [41,61)
    int*  rowcnt    = (int*)(ws + ((size_t)61 << 20));      // 16 KB
    u64*  ovf2      = (u64*)(ws + ((size_t)62 << 20));      // 1 MB  [62,63)
    u16*  Wbf       = (u16*)(ws + ((size_t)64 << 20));      // 32 MB [64,96)
    u16*  xbf       = (u16*)(ws + ((size_t)96 << 20));      // 4 MB  [96,100)
    float* y        = (float*)d_out;

    conv_x<<<(BATCH * IN_F / 4) / 256, 256, 0, stream>>>(x, xbf, gcur);
    int nblk = (nnz + CHUNK - 1) / CHUNK;
    bucket_scatter<<<nblk, 256, 0, stream>>>(row, col, w1d, gcur, bins, govf_cnt, govf, nnz);
    split_bucket<<<NB, 256, 0, stream>>>(gcur, bins, govf_cnt, govf, rowbins, rowcnt, ovf2_cnt, ovf2);
    build_row2<<<OUT_F, 256, 0, stream>>>(rowbins, rowcnt, ovf2_cnt, ovf2, Wbf);
    gemm_part<<<512, 256, 0, stream>>>(xbf, Wbf, part);
    reduce_bias<<<(BATCH * OUT_F / 4) / 256, 256, 0, stream>>>(part, bias, y);
}

// Round 10
// 102.921 us; speedup vs baseline: 1.7657x; 1.0049x over previous
//
#include <hip/hip_runtime.h>
#include <hip/hip_bf16.h>

typedef unsigned short u16;
typedef unsigned long long u64;
typedef __attribute__((ext_vector_type(4))) float f32x4;
typedef __attribute__((ext_vector_type(8))) short bf16x8;

#define IN_F   4096
#define OUT_F  4096
#define BATCH  512

#define BM 128
#define BN 128
#define BK 64
#define KSPLIT 4
#define KC (IN_F / KSPLIT)     // 1024
#define NSTEPS (KC / BK)       // 16

#define NXCD    8
#define NB      256            // coarse buckets, 16 rows each
#define CHUNK   2048           // entries per bucket_scatter block
#define LCAP    24             // LDS bucket cap (mean 8, +5.6 sigma)
#define SEGCAP  2048           // per (xcd,bucket) seg cap
#define RCAP    640            // per-row list cap (mean 390, +12.7 sigma)
#define GOVFCAP (1024*1024)
#define OVF2CAP (128*1024)
#define NCTR    (NXCD * NB + 2)   // gcur + govf_cnt + ovf2_cnt

__device__ inline u16 f2bf(float f) {
    __hip_bfloat16 h = __float2bfloat16(f);   // RNE
    u16 u; __builtin_memcpy(&u, &h, 2); return u;
}

// conv_x + counter clear (in-kernel; avoids an extra fill dispatch).
__global__ __launch_bounds__(256) void conv_x(const float* __restrict__ x,
                                              u16* __restrict__ xbf,
                                              int* __restrict__ ctrs) {
    const int tid = threadIdx.x;
    if (blockIdx.x == 0) {
        for (int j = tid; j < NCTR; j += 256) ctrs[j] = 0;
    }
    int i = blockIdx.x * 256 + tid;
    float4 v = ((const float4*)x)[i];
    ushort4 o;
    o.x = f2bf(v.x); o.y = f2bf(v.y); o.z = f2bf(v.z); o.w = f2bf(v.w);
    ((ushort4*)xbf)[i] = o;
}

// Phase 1: LDS-aggregated coarse binning, weight inlined.
// bin entry: (i<<32)|(rl<<28)|(col<<16)|wbf.  govf: (i<<40)|(row<<28)|(col<<16)|wbf.
__global__ __launch_bounds__(256) void bucket_scatter(const int* __restrict__ row,
                                                      const int* __restrict__ col,
                                                      const float* __restrict__ w,
                                                      int* __restrict__ gcur,
                                                      u64* __restrict__ bins,
                                                      int* __restrict__ govf_cnt,
                                                      u64* __restrict__ govf, int nnz) {
    __shared__ u64 lbin[NB][LCAP];   // 48 KB
    __shared__ int lcur[NB];
    const int xcd = __builtin_amdgcn_s_getreg(20 | (3 << 11)) & (NXCD - 1);
    const int tid = threadIdx.x;
    lcur[tid] = 0;
    __syncthreads();

    int base = blockIdx.x * CHUNK + tid * 8;
    if (base + 8 <= nnz) {
        int4 r0 = ((const int4*)(row + base))[0];
        int4 r1 = ((const int4*)(row + base))[1];
        int4 c0 = ((const int4*)(col + base))[0];
        int4 c1 = ((const int4*)(col + base))[1];
        float4 w0 = ((const float4*)(w + base))[0];
        float4 w1 = ((const float4*)(w + base))[1];
        int rs[8] = {r0.x, r0.y, r0.z, r0.w, r1.x, r1.y, r1.z, r1.w};
        int cs[8] = {c0.x, c0.y, c0.z, c0.w, c1.x, c1.y, c1.z, c1.w};
        float wsv[8] = {w0.x, w0.y, w0.z, w0.w, w1.x, w1.y, w1.z, w1.w};
#pragma unroll
        for (int j = 0; j < 8; j++) {
            int rr = rs[j], cc = cs[j], i = base + j;
            u64 wb = (u64)f2bf(wsv[j]);
            int bk = rr >> 4;
            int p = atomicAdd(&lcur[bk], 1);
            if (p < LCAP) {
                lbin[bk][p] = ((u64)i << 32) | ((u64)(rr & 15) << 28) | ((u64)cc << 16) | wb;
            } else {
                int o = atomicAdd(govf_cnt, 1);
                if (o < GOVFCAP) govf[o] = ((u64)i << 40) | ((u64)rr << 28) | ((u64)cc << 16) | wb;
            }
        }
    } else {
        int e = nnz < base + 8 ? nnz : base + 8;
        for (int i = base; i < e; i++) {
            int rr = row[i], cc = col[i];
            u64 wb = (u64)f2bf(w[i]);
            int bk = rr >> 4;
            int p = atomicAdd(&lcur[bk], 1);
            if (p < LCAP) {
                lbin[bk][p] = ((u64)i << 32) | ((u64)(rr & 15) << 28) | ((u64)cc << 16) | wb;
            } else {
                int o = atomicAdd(govf_cnt, 1);
                if (o < GOVFCAP) govf[o] = ((u64)i << 40) | ((u64)rr << 28) | ((u64)cc << 16) | wb;
            }
        }
    }
    __syncthreads();

    int cnt = lcur[tid];
    if (cnt > LCAP) cnt = LCAP;
    if (cnt > 0) {
        int gb = (xcd << 8) | tid;
        int b0 = atomicAdd(&gcur[gb], cnt);
        u64* seg = bins + (size_t)gb * SEGCAP;
        for (int k = 0; k < cnt; k++) {
            u64 e = lbin[tid][k];
            int p = b0 + k;
            if (p < SEGCAP) {
                seg[p] = e;
            } else {
                int rr = (tid << 4) | ((int)(e >> 28) & 15);
                int o = atomicAdd(govf_cnt, 1);
                if (o < GOVFCAP) govf[o] = ((e >> 32) << 40) | ((u64)rr << 28) | (e & 0x0FFFFFFF);
            }
        }
    }
}

// Phase 2a: one block per bucket. Read the 8 segs ONCE, route to 16 per-row
// LDS lists, flush each contiguously to rowbins. Overflow -> ovf2.
__global__ __launch_bounds__(256) void split_bucket(const int* __restrict__ gcur,
                                                    const u64* __restrict__ bins,
                                                    const int* __restrict__ govf_cnt,
                                                    const u64* __restrict__ govf,
                                                    u64* __restrict__ rowbins,
                                                    int* __restrict__ rowcnt,
                                                    int* __restrict__ ovf2_cnt,
                                                    u64* __restrict__ ovf2) {
    __shared__ u64 lists[16][RCAP];   // 80 KB
    __shared__ int lcur[16];
    const int bucket = blockIdx.x;
    const int tid = threadIdx.x;
    if (tid < 16) lcur[tid] = 0;
    __syncthreads();

#pragma unroll
    for (int xcd = 0; xcd < NXCD; xcd++) {
        int gb = (xcd << 8) | bucket;
        int cnt = gcur[gb];
        if (cnt > SEGCAP) cnt = SEGCAP;
        const u64* seg = bins + (size_t)gb * SEGCAP;
        for (int k = tid; k < cnt; k += 256) {
            u64 e = seg[k];
            int rl = (int)(e >> 28) & 15;
            int p = atomicAdd(&lcur[rl], 1);
            if (p < RCAP) lists[rl][p] = e;
            else {
                int rr = (bucket << 4) | rl;
                int o = atomicAdd(ovf2_cnt, 1);
                if (o < OVF2CAP) ovf2[o] = ((e >> 32) << 40) | ((u64)rr << 28) | (e & 0x0FFFFFFF);
            }
        }
    }
    int ovfn = *govf_cnt;
    if (ovfn > GOVFCAP) ovfn = GOVFCAP;
    for (int k = tid; k < ovfn; k += 256) {
        u64 e = govf[k];
        int rr = (int)(e >> 28) & 4095;
        if ((rr >> 4) == bucket) {
            u64 e2 = ((e >> 40) << 32) | ((u64)(rr & 15) << 28) | (e & 0x0FFFFFFF);
            int rl = rr & 15;
            int p = atomicAdd(&lcur[rl], 1);
            if (p < RCAP) lists[rl][p] = e2;
            else { int o = atomicAdd(ovf2_cnt, 1); if (o < OVF2CAP) ovf2[o] = ((e2 >> 32) << 40) | ((u64)rr << 28) | (e2 & 0x0FFFFFFF); }
        }
    }
    __syncthreads();

    for (int rl = 0; rl < 16; rl++) {
        int cnt = lcur[rl];
        if (cnt > RCAP) cnt = RCAP;
        int rowg = (bucket << 4) | rl;
        u64* dst = rowbins + (size_t)rowg * RCAP;
        for (int k = tid; k < cnt; k += 256) dst[k] = lists[rl][k];
        if (tid == 0) rowcnt[rowg] = cnt;
    }
}

// Phase 2b: one block per row. Resolve last-write-wins via
// atomicMax(aux[col], (i<<16)|wbf) — unique i => order-independent. Emit row.
__global__ __launch_bounds__(256) void build_row2(const u64* __restrict__ rowbins,
                                                  const int* __restrict__ rowcnt,
                                                  const int* __restrict__ ovf2_cnt,
                                                  const u64* __restrict__ ovf2,
                                                  u16* __restrict__ Wbf) {
    __shared__ u64 aux[IN_F];   // 32 KB
    const int rowg = blockIdx.x;
    const int tid = threadIdx.x;

#pragma unroll
    for (int j = 0; j < IN_F / 256 / 2; j++)
        ((ulonglong2*)aux)[tid * 8 + j] = (ulonglong2){0ull, 0ull};
    __syncthreads();

    int cnt = rowcnt[rowg];
    const u64* seg = rowbins + (size_t)rowg * RCAP;
    for (int k = tid; k < cnt; k += 256) {
        u64 e = seg[k];
        atomicMax(&aux[(int)(e >> 16) & 4095], ((e >> 32) << 16) | (e & 0xFFFF));
    }
    int o2 = *ovf2_cnt;
    if (o2 > OVF2CAP) o2 = OVF2CAP;
    for (int k = tid; k < o2; k += 256) {
        u64 e = ovf2[k];
        if (((int)(e >> 28) & 4095) == rowg)
            atomicMax(&aux[(int)(e >> 16) & 4095], ((e >> 40) << 16) | (e & 0xFFFF));
    }
    __syncthreads();

    int base = tid * 16;
    ushort4 o[4];
#pragma unroll
    for (int j = 0; j < 16; j++)
        ((u16*)o)[j] = (u16)(aux[base + j] & 0xFFFF);
    uint4* dst = (uint4*)(Wbf + (size_t)rowg * IN_F + base);
    dst[0] = ((const uint4*)o)[0];
    dst[1] = ((const uint4*)o)[1];
}

// Partial GEMM, 128x128 tile, 4 waves, KSPLIT=4 -> 512 blocks = 2/CU.
// ROUND-10 FIX: true counted-vmcnt 2-phase. Old order (STAGE; compute;
// vmcnt(0); barrier) drained the just-issued prefetch AFTER compute —
// full HBM latency exposed per K-step. New order: STAGE(next); vmcnt(8)
// [waits only for tile t, leaves t+1's 8 loads in flight]; barrier;
// compute; barrier. Prefetch latency hides under compute.
__global__ __launch_bounds__(256) void gemm_part(const u16* __restrict__ A,
                                                 const u16* __restrict__ B,
                                                 float* __restrict__ part) {
    __shared__ u16 As[2][BM * BK];   // 2 x 16 KB
    __shared__ u16 Bs[2][BN * BK];   // 2 x 16 KB => 64 KB
    const int L   = blockIdx.x;
    const int xx  = L & 7;
    const int rst = L >> 3;
    const int m   = rst & 3;
    const int g   = ((rst >> 2) << 3) | xx;   // g%8==L%8 -> XCD-affine B panel
    const int n   = g & 31;
    const int kc  = g >> 5;
    const int m0  = m * BM;
    const int n0  = n * BN;
    const int kt0 = kc * KC;

    const int tid  = threadIdx.x;
    const int lane = tid & 63;
    const int wave = tid >> 6;
    const int wm = wave >> 1, wn = wave & 1;   // 2x2 waves, wave tile 64x64
    const int r15 = lane & 15, khi = lane >> 4;

    const u16* srcA[4]; const u16* srcB[4]; int dstO[4];
#pragma unroll
    for (int it = 0; it < 4; it++) {
        int o = tid * 16 + it * 4096;
        int rr = o >> 7, lblk = (o >> 4) & 7;
        srcA[it] = A + (size_t)(m0 + rr) * IN_F + kt0 + ((lblk ^ (rr & 7)) << 3);
        srcB[it] = B + (size_t)(n0 + rr) * IN_F + kt0 + ((lblk ^ (rr & 7)) << 3);
        dstO[it] = o >> 1;
    }

#define STAGE(buf, kk)                                                               \
    do {                                                                             \
        _Pragma("unroll")                                                            \
        for (int it = 0; it < 4; it++)                                               \
            __builtin_amdgcn_global_load_lds(                                        \
                (const __attribute__((address_space(1))) void*)(srcA[it] + (kk)),    \
                (__attribute__((address_space(3))) void*)(&As[buf][dstO[it]]),       \
                16, 0, 0);                                                           \
        _Pragma("unroll")                                                            \
        for (int it = 0; it < 4; it++)                                               \
            __builtin_amdgcn_global_load_lds(                                        \
                (const __attribute__((address_space(1))) void*)(srcB[it] + (kk)),    \
                (__attribute__((address_space(3))) void*)(&Bs[buf][dstO[it]]),       \
                16, 0, 0);                                                           \
    } while (0)

    f32x4 acc[4][4];
#pragma unroll
    for (int mi = 0; mi < 4; mi++)
#pragma unroll
        for (int nj = 0; nj < 4; nj++) acc[mi][nj] = (f32x4){0.f, 0.f, 0.f, 0.f};

    STAGE(0, 0);   // 8 loads outstanding; no drain here

    for (int t = 0; t < NSTEPS; ++t) {
        const int cur = t & 1;
        if (t + 1 < NSTEPS) {
            STAGE(cur ^ 1, (t + 1) * BK);                      // 8 more in flight
            asm volatile("s_waitcnt vmcnt(8)" ::: "memory");   // tile t landed; t+1 stays in flight
        } else {
            asm volatile("s_waitcnt vmcnt(0)" ::: "memory");   // last tile
        }
        __builtin_amdgcn_s_barrier();                          // all waves' tile-t writes visible

        const char* as = (const char*)&As[cur][0];
        const char* bs = (const char*)&Bs[cur][0];
#pragma unroll
        for (int ks = 0; ks < 2; ks++) {
            bf16x8 a[4], b[4];
#pragma unroll
            for (int mi = 0; mi < 4; mi++) {
                int rowi = wm * 64 + mi * 16 + r15;
                a[mi] = *(const bf16x8*)(as + rowi * 128 + (((ks * 4 + khi) ^ (rowi & 7)) << 4));
            }
#pragma unroll
            for (int nj = 0; nj < 4; nj++) {
                int rowi = wn * 64 + nj * 16 + r15;
                b[nj] = *(const bf16x8*)(bs + rowi * 128 + (((ks * 4 + khi) ^ (rowi & 7)) << 4));
            }
#pragma unroll
            for (int mi = 0; mi < 4; mi++)
#pragma unroll
                for (int nj = 0; nj < 4; nj++)
                    acc[mi][nj] = __builtin_amdgcn_mfma_f32_16x16x32_bf16(a[mi], b[nj], acc[mi][nj], 0, 0, 0);
        }
        __builtin_amdgcn_s_barrier();   // all waves done reading cur -> next iter may stage into it
    }
#undef STAGE

    float* P = part + (size_t)kc * BATCH * OUT_F;
#pragma unroll
    for (int nj = 0; nj < 4; nj++) {
        int colg = n0 + wn * 64 + nj * 16 + r15;
#pragma unroll
        for (int mi = 0; mi < 4; mi++) {
#pragma unroll
            for (int j = 0; j < 4; j++) {
                int rowg = m0 + wm * 64 + mi * 16 + khi * 4 + j;
                P[(size_t)rowg * OUT_F + colg] = acc[mi][nj][j];
            }
        }
    }
}

// y = sum_kc part[kc] + bias
__global__ __launch_bounds__(256) void reduce_bias(const float* __restrict__ part,
                                                   const float* __restrict__ bias,
                                                   float* __restrict__ y) {
    int i = blockIdx.x * 256 + threadIdx.x;
    const size_t STRIDE = (size_t)BATCH * OUT_F / 4;
    f32x4 s = ((const f32x4*)part)[i];
#pragma unroll
    for (int k = 1; k < KSPLIT; k++) s += ((const f32x4*)part)[i + k * STRIDE];
    int col4 = (i * 4) & (OUT_F - 1);
    f32x4 b = *(const f32x4*)&bias[col4];
    ((f32x4*)y)[i] = s + b;
}

extern "C" void kernel_launch(void* const* d_in, const int* in_sizes, int n_in,
                              void* d_out, int out_size, void* d_ws, size_t ws_size,
                              hipStream_t stream) {
    const float* x    = (const float*)d_in[0];
    const float* w1d  = (const float*)d_in[1];
    const float* bias = (const float*)d_in[2];
    const int*   row  = (const int*)d_in[3];
    const int*   col  = (const int*)d_in[4];
    const int nnz = in_sizes[1];

    char* ws        = (char*)d_ws;
    u64*  bins      = (u64*)ws;                             // 32 MB [0,32) — dead after split_bucket
    float* part     = (float*)ws;                           // 32 MB [0,32) — overlays bins
    int*  gcur      = (int*)(ws + ((size_t)32 << 20));      // 8 KB (+2 cnts = NCTR ints)
    int*  govf_cnt  = gcur + NXCD * NB;
    int*  ovf2_cnt  = govf_cnt + 1;
    u64*  govf      = (u64*)(ws + ((size_t)33 << 20));      // 8 MB  [33,41)
    u64*  rowbins   = (u64*)(ws + ((size_t)41 << 20));      // 20 MB [41,61)
    int*  rowcnt    = (int*)(ws + ((size_t)61 << 20));      // 16 KB
    u64*  ovf2      = (u64*)(ws + ((size_t)62 << 20));      // 1 MB  [62,63)
    u16*  Wbf       = (u16*)(ws + ((size_t)64 << 20));      // 32 MB [64,96)
    u16*  xbf       = (u16*)(ws + ((size_t)96 << 20));      // 4 MB  [96,100)
    float* y        = (float*)d_out;

    conv_x<<<(BATCH * IN_F / 4) / 256, 256, 0, stream>>>(x, xbf, gcur);
    int nblk = (nnz + CHUNK - 1) / CHUNK;
    bucket_scatter<<<nblk, 256, 0, stream>>>(row, col, w1d, gcur, bins, govf_cnt, govf, nnz);
    split_bucket<<<NB, 256, 0, stream>>>(gcur, bins, govf_cnt, govf, rowbins, rowcnt, ovf2_cnt, ovf2);
    build_row2<<<OUT_F, 256, 0, stream>>>(rowbins, rowcnt, ovf2_cnt, ovf2, Wbf);
    gemm_part<<<512, 256, 0, stream>>>(xbf, Wbf, part);
    reduce_bias<<<(BATCH * OUT_F / 4) / 256, 256, 0, stream>>>(part, bias, y);
}